// Round 4
// baseline (30.294 us; speedup 1.0000x reference)
//
#include <hip/hip_runtime.h>

// ParallelLatticeModel v4: single fused kernel (no prep), selection-based
// calibration, 4 threads/row for 2x wave count.
//
// B=131072 rows, D=16 features, 4 lattices x 4 dims (16 corners), E=24 cols,
// K=16 calibration keypoints.
//
// Block = 256 threads = 4 waves, 64 rows. Wave w handles feature quarter w
// (= lattice w) for all 64 rows, then M-tile w in phase 2.
//   phase 0: stage k1 as fp16 MFMA B-fragments + k2 (fp32, zero-padded) in LDS
//   phase 1: calibrate 4 features via branchless segment-select
//            (cmp + cndmask cascade over SGPR keypoints, one fp32 divide),
//            build 16 multilinear corner weights, write fp16 A-frags to LDS.
//   phase 2: 4 lattices x 2 N-tiles of v_mfma_f32_16x16x16_f16; layer-2
//            lerp chain on VALU per accumulator reg; k2 read per-lane from
//            LDS (e = lane&15 matches C col). C: col=lane&15, row=4*(lane>>4)+r.

typedef _Float16 f16x4 __attribute__((ext_vector_type(4)));
typedef float f32x4 __attribute__((ext_vector_type(4)));

namespace {
constexpr int kD = 16, kE = 24, kK = 16, kNV = 16;
constexpr int kThreads = 256;
constexpr int kRPB = 64;             // rows per block
constexpr int kK2S = 20;             // sK2 row stride (bank spread)
}

__global__ __launch_bounds__(kThreads, 4) void lattice_fwd(
    const float* __restrict__ x,
    const float* __restrict__ cal_kp,    // [D][K]
    const float* __restrict__ cal_vals,  // [D][K]
    const float* __restrict__ k1,        // [E][4][16]
    const float* __restrict__ k2,        // [E][16]
    float* __restrict__ out)             // [B][E]
{
    __shared__ f16x4 sW[4 * 4 * 64];     // [mtile][lattice][lane]  8 KB
    __shared__ f16x4 sK1[4 * 2 * 64];    // [lattice][ntile][lane]  4 KB
    __shared__ float sK2[32 * kK2S];     // [e][20]               2.5 KB

    const int tid  = threadIdx.x;
    const int lane = tid & 63;
    const int wv   = __builtin_amdgcn_readfirstlane(tid >> 6);   // 0..3

    // ---------------- phase 0: stage k1 (B-frags) and k2 ----------------
    // B-frag (lattice l, ntile n): lane ls holds B[k=4*(ls>>4)+j][col=16n+(ls&15)]
    #pragma unroll
    for (int s0 = 0; s0 < 2; ++s0) {
        int s  = tid + s0 * kThreads;    // 0..511
        int l  = s >> 7;
        int n  = (s >> 6) & 1;
        int ls = s & 63;
        int e  = n * 16 + (ls & 15);
        int g  = ls >> 4;
        f16x4 v = {(_Float16)0.f, (_Float16)0.f, (_Float16)0.f, (_Float16)0.f};
        if (e < kE) {
            const float* src = k1 + ((size_t)(e * 4 + l) * kNV + 4 * g);
            v[0] = (_Float16)src[0]; v[1] = (_Float16)src[1];
            v[2] = (_Float16)src[2]; v[3] = (_Float16)src[3];
        }
        sK1[s] = v;
    }
    {   // k2: 32 rows (e>=24 zero-filled so idle lanes read harmless data)
        int e = tid >> 3, j = tid & 7;
        float a = 0.f, b = 0.f;
        if (e < kE) { a = k2[e * kNV + j]; b = k2[e * kNV + j + 8]; }
        sK2[e * kK2S + j]     = a;
        sK2[e * kK2S + j + 8] = b;
    }

    // ------------- phase 1: calibrate 4 features, build A-frags -------------
    const size_t row = (size_t)blockIdx.x * kRPB + lane;
    float xr[4];
    {
        const f32x4* xp = reinterpret_cast<const f32x4*>(x + row * kD + wv * 4);
        f32x4 v = xp[0];
        xr[0] = v[0]; xr[1] = v[1]; xr[2] = v[2]; xr[3] = v[3];
    }

    // piecewise-linear calibration by branchless segment selection:
    // j = max{k: x >= kp[k]}; xc = v[j] + (v[j+1]-v[j]) * clamp((x-kp[j])/(kp[j+1]-kp[j]),0,1)
    float xc[4];
    #pragma unroll
    for (int i = 0; i < 4; ++i) {
        const int d = wv * 4 + i;                     // wave-uniform -> s_loads
        const float* kp = cal_kp  + (size_t)d * kK;
        const float* cv = cal_vals + (size_t)d * kK;
        float xv  = xr[i];
        float kp0 = kp[0], kp1 = kp[1], v0 = cv[0], v1 = cv[1];
        #pragma unroll
        for (int k = 1; k < 15; ++k) {
            bool c = xv >= kp[k];                     // v_cmp + 4x v_cndmask
            kp0 = c ? kp[k]     : kp0;
            kp1 = c ? kp[k + 1] : kp1;
            v0  = c ? cv[k]     : v0;
            v1  = c ? cv[k + 1] : v1;
        }
        float t = (xv - kp0) / (kp1 - kp0);           // exact fp32 divide
        t = fminf(fmaxf(t, 0.0f), 1.0f);              // handles x outside ends
        xc[i] = fmaf(v1 - v0, t, v0);                 // in [0,1] (monotone vals)
    }

    // multilinear corner weights for lattice wv (dim0 = MSB of corner index)
    float wf[16];
    {
        float a = xc[0], b = xc[1], c = xc[2], d = xc[3];
        float t2[2] = {1.0f - a, a};
        float t4[4];
        #pragma unroll
        for (int j = 0; j < 2; ++j) { t4[2*j] = t2[j]*(1.0f-b); t4[2*j+1] = t2[j]*b; }
        float t8[8];
        #pragma unroll
        for (int j = 0; j < 4; ++j) { t8[2*j] = t4[j]*(1.0f-c); t8[2*j+1] = t4[j]*c; }
        #pragma unroll
        for (int j = 0; j < 8; ++j) { wf[2*j] = t8[j]*(1.0f-d); wf[2*j+1] = t8[j]*d; }
    }

    // A-frag: lane' = (row&15) + 16g holds A[row&15][k=4g+j] for M-tile row>>4
    {
        int m = lane >> 4, r15 = lane & 15;
        #pragma unroll
        for (int g = 0; g < 4; ++g) {
            f16x4 v;
            v[0] = (_Float16)wf[4*g+0]; v[1] = (_Float16)wf[4*g+1];
            v[2] = (_Float16)wf[4*g+2]; v[3] = (_Float16)wf[4*g+3];
            sW[(m * 4 + wv) * 64 + r15 + 16 * g] = v;
        }
    }

    __syncthreads();

    // ---------------- phase 2: MFMA layer-1 + VALU layer-2 ----------------
    f16x4 af[4];                          // this wave's M-tile, 4 lattices
    #pragma unroll
    for (int l = 0; l < 4; ++l) af[l] = sW[(wv * 4 + l) * 64 + lane];

    f16x4 bf[4][2];
    #pragma unroll
    for (int l = 0; l < 4; ++l)
        #pragma unroll
        for (int n = 0; n < 2; ++n) bf[l][n] = sK1[(l * 2 + n) * 64 + lane];

    const size_t outBase = (size_t)blockIdx.x * kRPB + wv * 16;

    #pragma unroll
    for (int n = 0; n < 2; ++n) {
        const int e = n * 16 + (lane & 15);
        const bool valid = (e < kE);
        float kb[16];
        {
            const f32x4* kp2 = reinterpret_cast<const f32x4*>(&sK2[e * kK2S]);
            #pragma unroll
            for (int j = 0; j < 4; ++j) {
                f32x4 t = kp2[j];
                kb[4*j+0]=t[0]; kb[4*j+1]=t[1]; kb[4*j+2]=t[2]; kb[4*j+3]=t[3];
            }
        }
        float db[8];
        #pragma unroll
        for (int j = 0; j < 8; ++j) db[j] = kb[2*j+1] - kb[2*j];

        f32x4 acc[4];
        #pragma unroll
        for (int l = 0; l < 4; ++l)
            acc[l] = __builtin_amdgcn_mfma_f32_16x16x16f16(
                af[l], bf[l][n], (f32x4){0.f, 0.f, 0.f, 0.f}, 0, 0, 0);

        #pragma unroll
        for (int r = 0; r < 4; ++r) {
            float h0 = fminf(fmaxf(acc[0][r], 0.0f), 1.0f);
            float h1 = fminf(fmaxf(acc[1][r], 0.0f), 1.0f);
            float h2 = fminf(fmaxf(acc[2][r], 0.0f), 1.0f);
            float h3 = fminf(fmaxf(acc[3][r], 0.0f), 1.0f);
            float v8[8];
            #pragma unroll
            for (int j = 0; j < 8; ++j) v8[j] = fmaf(h3, db[j], kb[2*j]);
            float v4[4];
            #pragma unroll
            for (int j = 0; j < 4; ++j) v4[j] = fmaf(h2, v8[2*j+1]-v8[2*j], v8[2*j]);
            float v2[2];
            #pragma unroll
            for (int j = 0; j < 2; ++j) v2[j] = fmaf(h1, v4[2*j+1]-v4[2*j], v4[2*j]);
            float o = fmaf(h0, v2[1]-v2[0], v2[0]);
            if (valid) {
                size_t orow = outBase + ((lane >> 4) << 2) + r;
                out[orow * kE + e] = o;
            }
        }
    }
}

extern "C" void kernel_launch(void* const* d_in, const int* in_sizes, int n_in,
                              void* d_out, int out_size, void* d_ws, size_t ws_size,
                              hipStream_t stream) {
    const float* x        = (const float*)d_in[0];
    const float* cal_kp   = (const float*)d_in[1];
    const float* cal_vals = (const float*)d_in[2];
    const float* k1       = (const float*)d_in[3];
    const float* k2       = (const float*)d_in[4];
    float* out = (float*)d_out;

    hipLaunchKernelGGL(lattice_fwd, dim3(131072 / kRPB), dim3(kThreads), 0, stream,
                       x, cal_kp, cal_vals, k1, k2, out);
}

// Round 5
// 17.014 us; speedup vs baseline: 1.7806x; 1.7806x over previous
//
#include <hip/hip_runtime.h>

// ParallelLatticeModel v5: single kernel; v3's table-based calibration with
// per-block LDS tables (no prep kernel, no SGPR table pressure); v4's
// 64-row/block high-occupancy structure; verified MFMA layouts.
//
// B=131072 rows, D=16 features, 4 lattices x 4 dims (16 corners), E=24 cols,
// K=16 calibration keypoints.
//
// Block = 256 threads = 4 waves, 64 rows. Wave w = feature quarter / lattice w
// for all 64 rows; M-tile w in phase 2.
//   phase 0: stage (a) cal segment table {kp,dx,slope} float4 x 240 (each of
//            240 threads computes one entry, one divide), (b) k1 as fp16 MFMA
//            B-fragments, (c) k2 rows (fp32, zero-padded) -> LDS.
//   phase 1: calibrate 4 features: acc += slope*clamp(x-kp,0,dx) per segment,
//            3 VALU + 1 broadcast ds_read_b128 per segment (all-VGPR ops);
//            build 16 multilinear corner weights; write fp16 A-frags to LDS.
//   phase 2: 4 lattices x 2 N-tiles of v_mfma_f32_16x16x16_f16 (K=16 exact);
//            layer-2 lerp chain on VALU; k2 per-lane from LDS (e = lane&15
//            = C col). C layout: col=lane&15, row=4*(lane>>4)+r (verified).

typedef _Float16 f16x4 __attribute__((ext_vector_type(4)));
typedef float f32x4 __attribute__((ext_vector_type(4)));

namespace {
constexpr int kD = 16, kE = 24, kK = 16, kNV = 16, kNSeg = 15;
constexpr int kThreads = 256;
constexpr int kRPB = 64;             // rows per block
constexpr int kK2S = 20;             // sK2 row stride (bank spread)
}

__global__ __launch_bounds__(kThreads, 4) void lattice_fwd(
    const float* __restrict__ x,
    const float* __restrict__ cal_kp,    // [D][K]
    const float* __restrict__ cal_vals,  // [D][K]
    const float* __restrict__ k1,        // [E][4][16]
    const float* __restrict__ k2,        // [E][16]
    float* __restrict__ out)             // [B][E]
{
    __shared__ f32x4 sCal[kD * kNSeg];   // {kp, dx, slope, v0} per (d,seg) 3.75KB
    __shared__ f16x4 sW[4 * 4 * 64];     // [mtile][lattice][lane]  8 KB
    __shared__ f16x4 sK1[4 * 2 * 64];    // [lattice][ntile][lane]  4 KB
    __shared__ float sK2[32 * kK2S];     // [e][20]               2.5 KB

    const int tid  = threadIdx.x;
    const int lane = tid & 63;
    const int wv   = __builtin_amdgcn_readfirstlane(tid >> 6);   // 0..3

    // prefetch this thread's x slice first (overlaps staging)
    const size_t row = (size_t)blockIdx.x * kRPB + lane;
    f32x4 xin = *reinterpret_cast<const f32x4*>(x + row * kD + wv * 4);

    // ---------------- phase 0: stage tables ----------------
    // (a) calibration segment table: one entry per thread (240 of 256)
    if (tid < kD * kNSeg) {
        int d = tid / kNSeg;
        int k = tid - d * kNSeg;
        float kp0 = cal_kp[d * kK + k];
        float kp1 = cal_kp[d * kK + k + 1];
        float v0  = cal_vals[d * kK + k];
        float v1  = cal_vals[d * kK + k + 1];
        float dx  = kp1 - kp0;
        float slope = (dx > 0.0f) ? (v1 - v0) / dx : 0.0f;
        f32x4 ent = {kp0, dx, slope, (k == 0) ? v0 : 0.0f};
        sCal[tid] = ent;
    }
    // (b) k1 B-frags: lane ls holds B[k=4*(ls>>4)+j][col=16n+(ls&15)]
    #pragma unroll
    for (int s0 = 0; s0 < 2; ++s0) {
        int s  = tid + s0 * kThreads;    // 0..511
        int l  = s >> 7;
        int n  = (s >> 6) & 1;
        int ls = s & 63;
        int e  = n * 16 + (ls & 15);
        int g  = ls >> 4;
        f16x4 v = {(_Float16)0.f, (_Float16)0.f, (_Float16)0.f, (_Float16)0.f};
        if (e < kE) {
            const float* src = k1 + ((size_t)(e * 4 + l) * kNV + 4 * g);
            v[0] = (_Float16)src[0]; v[1] = (_Float16)src[1];
            v[2] = (_Float16)src[2]; v[3] = (_Float16)src[3];
        }
        sK1[s] = v;
    }
    // (c) k2 rows, zero-padded to 32
    {
        int e = tid >> 3, j = tid & 7;
        float a = 0.f, b = 0.f;
        if (e < kE) { a = k2[e * kNV + j]; b = k2[e * kNV + j + 8]; }
        sK2[e * kK2S + j]     = a;
        sK2[e * kK2S + j + 8] = b;
    }

    __syncthreads();

    // ------------- phase 1: calibrate 4 features, build A-frags -------------
    // interp(x) = v0 + sum_k slope_k * clamp(x - kp_k, 0, dx_k); then clip [0,1]
    float xc[4];
    #pragma unroll
    for (int i = 0; i < 4; ++i) {
        const int d = wv * 4 + i;                 // wave-uniform
        float xv  = xin[i];
        f32x4 e0  = sCal[d * kNSeg];              // broadcast ds_read_b128
        float acc = e0[3];                        // v0 of segment 0
        {
            float t = fminf(fmaxf(xv - e0[0], 0.0f), e0[1]);
            acc = fmaf(e0[2], t, acc);
        }
        #pragma unroll
        for (int k = 1; k < kNSeg; ++k) {
            f32x4 en = sCal[d * kNSeg + k];       // broadcast, all-VGPR
            float t = fminf(fmaxf(xv - en[0], 0.0f), en[1]);
            acc = fmaf(en[2], t, acc);
        }
        xc[i] = fminf(fmaxf(acc, 0.0f), 1.0f);    // clip_inputs=True
    }

    // multilinear corner weights for lattice wv (dim0 = MSB of corner index)
    float wf[16];
    {
        float a = xc[0], b = xc[1], c = xc[2], d = xc[3];
        float t2[2] = {1.0f - a, a};
        float t4[4];
        #pragma unroll
        for (int j = 0; j < 2; ++j) { t4[2*j] = t2[j]*(1.0f-b); t4[2*j+1] = t2[j]*b; }
        float t8[8];
        #pragma unroll
        for (int j = 0; j < 4; ++j) { t8[2*j] = t4[j]*(1.0f-c); t8[2*j+1] = t4[j]*c; }
        #pragma unroll
        for (int j = 0; j < 8; ++j) { wf[2*j] = t8[j]*(1.0f-d); wf[2*j+1] = t8[j]*d; }
    }

    // A-frag: lane' = (row&15) + 16g holds A[row&15][k=4g+j] for M-tile row>>4
    {
        int m = lane >> 4, r15 = lane & 15;
        #pragma unroll
        for (int g = 0; g < 4; ++g) {
            f16x4 v;
            v[0] = (_Float16)wf[4*g+0]; v[1] = (_Float16)wf[4*g+1];
            v[2] = (_Float16)wf[4*g+2]; v[3] = (_Float16)wf[4*g+3];
            sW[(m * 4 + wv) * 64 + r15 + 16 * g] = v;
        }
    }

    __syncthreads();

    // ---------------- phase 2: MFMA layer-1 + VALU layer-2 ----------------
    f16x4 af[4];                          // this wave's M-tile, 4 lattices
    #pragma unroll
    for (int l = 0; l < 4; ++l) af[l] = sW[(wv * 4 + l) * 64 + lane];

    f16x4 bf[4][2];
    #pragma unroll
    for (int l = 0; l < 4; ++l)
        #pragma unroll
        for (int n = 0; n < 2; ++n) bf[l][n] = sK1[(l * 2 + n) * 64 + lane];

    const size_t outBase = (size_t)blockIdx.x * kRPB + wv * 16;

    #pragma unroll
    for (int n = 0; n < 2; ++n) {
        const int e = n * 16 + (lane & 15);
        const bool valid = (e < kE);
        float kb[16];
        {
            const f32x4* kp2 = reinterpret_cast<const f32x4*>(&sK2[e * kK2S]);
            #pragma unroll
            for (int j = 0; j < 4; ++j) {
                f32x4 t = kp2[j];
                kb[4*j+0]=t[0]; kb[4*j+1]=t[1]; kb[4*j+2]=t[2]; kb[4*j+3]=t[3];
            }
        }
        float db[8];
        #pragma unroll
        for (int j = 0; j < 8; ++j) db[j] = kb[2*j+1] - kb[2*j];

        f32x4 acc[4];
        #pragma unroll
        for (int l = 0; l < 4; ++l)
            acc[l] = __builtin_amdgcn_mfma_f32_16x16x16f16(
                af[l], bf[l][n], (f32x4){0.f, 0.f, 0.f, 0.f}, 0, 0, 0);

        #pragma unroll
        for (int r = 0; r < 4; ++r) {
            float h0 = fminf(fmaxf(acc[0][r], 0.0f), 1.0f);
            float h1 = fminf(fmaxf(acc[1][r], 0.0f), 1.0f);
            float h2 = fminf(fmaxf(acc[2][r], 0.0f), 1.0f);
            float h3 = fminf(fmaxf(acc[3][r], 0.0f), 1.0f);
            float v8[8];
            #pragma unroll
            for (int j = 0; j < 8; ++j) v8[j] = fmaf(h3, db[j], kb[2*j]);
            float v4[4];
            #pragma unroll
            for (int j = 0; j < 4; ++j) v4[j] = fmaf(h2, v8[2*j+1]-v8[2*j], v8[2*j]);
            float v2[2];
            #pragma unroll
            for (int j = 0; j < 2; ++j) v2[j] = fmaf(h1, v4[2*j+1]-v4[2*j], v4[2*j]);
            float o = fmaf(h0, v2[1]-v2[0], v2[0]);
            if (valid) {
                size_t orow = outBase + ((lane >> 4) << 2) + r;
                out[orow * kE + e] = o;
            }
        }
    }
}

extern "C" void kernel_launch(void* const* d_in, const int* in_sizes, int n_in,
                              void* d_out, int out_size, void* d_ws, size_t ws_size,
                              hipStream_t stream) {
    const float* x        = (const float*)d_in[0];
    const float* cal_kp   = (const float*)d_in[1];
    const float* cal_vals = (const float*)d_in[2];
    const float* k1       = (const float*)d_in[3];
    const float* k2       = (const float*)d_in[4];
    float* out = (float*)d_out;

    hipLaunchKernelGGL(lattice_fwd, dim3(131072 / kRPB), dim3(kThreads), 0, stream,
                       x, cal_kp, cal_vals, k1, k2, out);
}

// Round 6
// 14.732 us; speedup vs baseline: 2.0563x; 1.1549x over previous
//
#include <hip/hip_runtime.h>

// ParallelLatticeModel v6: v5 + binary-search calibration (5 LDS ops + ~20
// VALU per feature instead of 15 broadcast ds_read_b128 + 46 VALU) and
// reduced phase-2 register pressure (bf per n-tile, launch_bounds (256,6)).
//
// B=131072 rows, D=16 features, 4 lattices x 4 dims (16 corners), E=24 cols,
// K=16 calibration keypoints.
//
// Block = 256 threads = 4 waves, 64 rows. Wave w = feature quarter / lattice
// w for all 64 rows; M-tile w in phase 2.
//   phase 0: stage (a) kp search rows [D][16] (+INF sentinel), (b) segment
//            entries {kp, slope, v0} [D][16] f32x4, (c) k1 as fp16 MFMA
//            B-frags, (d) k2 rows (fp32, zero-padded) -> LDS.
//   phase 1: per feature: 4-step binary search for segment j, one b128 entry
//            read, xc = clamp(v0 + slope*(x-kp), 0, 1)  (cal_vals[:,0]=0 and
//            [:,15]=1 exactly, so this matches np.interp ends + clip);
//            build 16 multilinear corner weights; write fp16 A-frags to LDS.
//   phase 2: 4 lattices x 2 N-tiles of v_mfma_f32_16x16x16_f16 (K=16 exact);
//            layer-2 lerp chain on VALU; k2 per-lane from LDS (e = lane&15
//            = C col). C layout: col=lane&15, row=4*(lane>>4)+r (verified).

typedef _Float16 f16x4 __attribute__((ext_vector_type(4)));
typedef float f32x4 __attribute__((ext_vector_type(4)));

namespace {
constexpr int kD = 16, kE = 24, kK = 16, kNV = 16;
constexpr int kThreads = 256;
constexpr int kRPB = 64;             // rows per block
constexpr int kK2S = 20;             // sK2 row stride (bank spread)
}

__global__ __launch_bounds__(kThreads, 6) void lattice_fwd(
    const float* __restrict__ x,
    const float* __restrict__ cal_kp,    // [D][K]
    const float* __restrict__ cal_vals,  // [D][K]
    const float* __restrict__ k1,        // [E][4][16]
    const float* __restrict__ k2,        // [E][16]
    float* __restrict__ out)             // [B][E]
{
    __shared__ float sKp[kD * 16];       // kp rows, +INF at k=15      1 KB
    __shared__ f32x4 sEnt[kD * 16];      // {kp, slope, v0, 0}         4 KB
    __shared__ f16x4 sW[4 * 4 * 64];     // [mtile][lattice][lane]     8 KB
    __shared__ f16x4 sK1[4 * 2 * 64];    // [lattice][ntile][lane]     4 KB
    __shared__ float sK2[32 * kK2S];     // [e][20]                  2.5 KB

    const int tid  = threadIdx.x;
    const int lane = tid & 63;
    const int wv   = __builtin_amdgcn_readfirstlane(tid >> 6);   // 0..3

    // prefetch this thread's x slice (overlaps staging)
    const size_t row = (size_t)blockIdx.x * kRPB + lane;
    f32x4 xin = *reinterpret_cast<const f32x4*>(x + row * kD + wv * 4);

    // ---------------- phase 0: stage tables ----------------
    // (a) kp search rows: sKp[d*16+k]; sentinel +INF at k=15
    sKp[tid] = ((tid & 15) == 15) ? __builtin_inff() : cal_kp[tid];
    // (b) segment entries (240 of 256 threads)
    if (tid < kD * 15) {
        int d = tid / 15;
        int k = tid - d * 15;
        float kp0 = cal_kp[d * kK + k];
        float kp1 = cal_kp[d * kK + k + 1];
        float v0  = cal_vals[d * kK + k];
        float v1  = cal_vals[d * kK + k + 1];
        float dxv = kp1 - kp0;
        float slope = (dxv > 0.0f) ? (v1 - v0) / dxv : 0.0f;
        sEnt[d * 16 + k] = (f32x4){kp0, slope, v0, 0.0f};
    }
    // (c) k1 B-frags: lane ls holds B[k=4*(ls>>4)+j][col=16n+(ls&15)]
    #pragma unroll
    for (int s0 = 0; s0 < 2; ++s0) {
        int s  = tid + s0 * kThreads;    // 0..511
        int l  = s >> 7;
        int n  = (s >> 6) & 1;
        int ls = s & 63;
        int e  = n * 16 + (ls & 15);
        int g  = ls >> 4;
        f16x4 v = {(_Float16)0.f, (_Float16)0.f, (_Float16)0.f, (_Float16)0.f};
        if (e < kE) {
            const float* src = k1 + ((size_t)(e * 4 + l) * kNV + 4 * g);
            v[0] = (_Float16)src[0]; v[1] = (_Float16)src[1];
            v[2] = (_Float16)src[2]; v[3] = (_Float16)src[3];
        }
        sK1[s] = v;
    }
    // (d) k2 rows, zero-padded to 32
    {
        int e = tid >> 3, j = tid & 7;
        float a = 0.f, b = 0.f;
        if (e < kE) { a = k2[e * kNV + j]; b = k2[e * kNV + j + 8]; }
        sK2[e * kK2S + j]     = a;
        sK2[e * kK2S + j + 8] = b;
    }

    __syncthreads();

    // ------------- phase 1: calibrate 4 features, build A-frags -------------
    float xc[4];
    #pragma unroll
    for (int i = 0; i < 4; ++i) {
        const int d = wv * 4 + i;                 // wave-uniform
        const float xv = xin[i];
        const float* kpb = &sKp[d * 16];
        int j = 0;
        #pragma unroll
        for (int s = 8; s >= 1; s >>= 1) {        // 4x: b32 read + cmp + cndmask
            float kps = kpb[j + s];
            j = (xv >= kps) ? j + s : j;          // ends at max{k<=14: x>=kp[k]}
        }
        f32x4 ent = sEnt[d * 16 + j];             // {kp, slope, v0}
        float t = fmaf(ent[1], xv - ent[0], ent[2]);
        xc[i] = fminf(fmaxf(t, 0.0f), 1.0f);      // interp ends + clip_inputs
    }

    // multilinear corner weights for lattice wv (dim0 = MSB of corner index)
    float wf[16];
    {
        float a = xc[0], b = xc[1], c = xc[2], d = xc[3];
        float t2[2] = {1.0f - a, a};
        float t4[4];
        #pragma unroll
        for (int j = 0; j < 2; ++j) { t4[2*j] = t2[j]*(1.0f-b); t4[2*j+1] = t2[j]*b; }
        float t8[8];
        #pragma unroll
        for (int j = 0; j < 4; ++j) { t8[2*j] = t4[j]*(1.0f-c); t8[2*j+1] = t4[j]*c; }
        #pragma unroll
        for (int j = 0; j < 8; ++j) { wf[2*j] = t8[j]*(1.0f-d); wf[2*j+1] = t8[j]*d; }
    }

    // A-frag: lane' = (row&15) + 16g holds A[row&15][k=4g+j] for M-tile row>>4
    {
        int m = lane >> 4, r15 = lane & 15;
        #pragma unroll
        for (int g = 0; g < 4; ++g) {
            f16x4 v;
            v[0] = (_Float16)wf[4*g+0]; v[1] = (_Float16)wf[4*g+1];
            v[2] = (_Float16)wf[4*g+2]; v[3] = (_Float16)wf[4*g+3];
            sW[(m * 4 + wv) * 64 + r15 + 16 * g] = v;
        }
    }

    __syncthreads();

    // ---------------- phase 2: MFMA layer-1 + VALU layer-2 ----------------
    f16x4 af[4];                          // this wave's M-tile, 4 lattices
    #pragma unroll
    for (int l = 0; l < 4; ++l) af[l] = sW[(wv * 4 + l) * 64 + lane];

    const size_t outBase = (size_t)blockIdx.x * kRPB + wv * 16;

    #pragma unroll
    for (int n = 0; n < 2; ++n) {
        const int e = n * 16 + (lane & 15);
        const bool valid = (e < kE);

        f16x4 bf[4];                      // load per n-tile (reg pressure)
        #pragma unroll
        for (int l = 0; l < 4; ++l) bf[l] = sK1[(l * 2 + n) * 64 + lane];

        float kb[16];
        {
            const f32x4* kp2 = reinterpret_cast<const f32x4*>(&sK2[e * kK2S]);
            #pragma unroll
            for (int j = 0; j < 4; ++j) {
                f32x4 t = kp2[j];
                kb[4*j+0]=t[0]; kb[4*j+1]=t[1]; kb[4*j+2]=t[2]; kb[4*j+3]=t[3];
            }
        }
        float db[8];
        #pragma unroll
        for (int j = 0; j < 8; ++j) db[j] = kb[2*j+1] - kb[2*j];

        f32x4 acc[4];
        #pragma unroll
        for (int l = 0; l < 4; ++l)
            acc[l] = __builtin_amdgcn_mfma_f32_16x16x16f16(
                af[l], bf[l], (f32x4){0.f, 0.f, 0.f, 0.f}, 0, 0, 0);

        #pragma unroll
        for (int r = 0; r < 4; ++r) {
            float h0 = fminf(fmaxf(acc[0][r], 0.0f), 1.0f);
            float h1 = fminf(fmaxf(acc[1][r], 0.0f), 1.0f);
            float h2 = fminf(fmaxf(acc[2][r], 0.0f), 1.0f);
            float h3 = fminf(fmaxf(acc[3][r], 0.0f), 1.0f);
            float v8[8];
            #pragma unroll
            for (int j = 0; j < 8; ++j) v8[j] = fmaf(h3, db[j], kb[2*j]);
            float v4[4];
            #pragma unroll
            for (int j = 0; j < 4; ++j) v4[j] = fmaf(h2, v8[2*j+1]-v8[2*j], v8[2*j]);
            float v2[2];
            #pragma unroll
            for (int j = 0; j < 2; ++j) v2[j] = fmaf(h1, v4[2*j+1]-v4[2*j], v4[2*j]);
            float o = fmaf(h0, v2[1]-v2[0], v2[0]);
            if (valid) {
                size_t orow = outBase + ((lane >> 4) << 2) + r;
                out[orow * kE + e] = o;
            }
        }
    }
}

extern "C" void kernel_launch(void* const* d_in, const int* in_sizes, int n_in,
                              void* d_out, int out_size, void* d_ws, size_t ws_size,
                              hipStream_t stream) {
    const float* x        = (const float*)d_in[0];
    const float* cal_kp   = (const float*)d_in[1];
    const float* cal_vals = (const float*)d_in[2];
    const float* k1       = (const float*)d_in[3];
    const float* k2       = (const float*)d_in[4];
    float* out = (float*)d_out;

    hipLaunchKernelGGL(lattice_fwd, dim3(131072 / kRPB), dim3(kThreads), 0, stream,
                       x, cal_kp, cal_vals, k1, k2, out);
}

// Round 7
// 14.227 us; speedup vs baseline: 2.1293x; 1.0355x over previous
//
#include <hip/hip_runtime.h>

// ParallelLatticeModel v7: wave<->M-tile remap (coalesced x, ONE barrier,
// wave-private A-frag staging), packed-f32 (v_pk_fma_f32) layer-2 epilogue,
// k2 staged as {evens, diffs}. Binary-search calibration from v6 kept.
//
// B=131072 rows, D=16 features, 4 lattices x 4 dims (16 corners), E=24 cols,
// K=16 calibration keypoints.
//
// Block = 256 threads = 4 waves, 64 rows. Wave wv owns rows 16wv..16wv+15.
// Phase 1: lane = r15 + 16q: thread calibrates features 4q..4q+3 of row r15
//          (= lattice q), builds 16 corner weights, writes fp16 A-frags to
//          the wave's own sW region (no barrier needed, just lgkmcnt).
// Phase 2: per wave: 4 lattices x 2 N-tiles of v_mfma_f32_16x16x16_f16;
//          C layout col=lane&15, row=4*(lane>>4)+r (test-verified v3-v6);
//          layer-2 lerp chain packed across row pairs with f32x2 ops.

typedef _Float16 f16x4 __attribute__((ext_vector_type(4)));
typedef float f32x4 __attribute__((ext_vector_type(4)));
typedef float f32x2 __attribute__((ext_vector_type(2)));

namespace {
constexpr int kD = 16, kE = 24, kK = 16, kNV = 16;
constexpr int kThreads = 256;
constexpr int kRPB = 64;             // rows per block
constexpr int kK2S = 20;             // sK2 row stride (bank spread)
}

static __device__ __forceinline__ f32x2 fma2(f32x2 a, f32x2 b, f32x2 c) {
#if __has_builtin(__builtin_elementwise_fma)
    return __builtin_elementwise_fma(a, b, c);
#else
    return (f32x2){fmaf(a[0], b[0], c[0]), fmaf(a[1], b[1], c[1])};
#endif
}
static __device__ __forceinline__ f32x2 fma2s(f32x2 a, float b, float c) {
    return fma2(a, (f32x2){b, b}, (f32x2){c, c});
}
static __device__ __forceinline__ f32x2 clamp01(f32x2 v) {
#if __has_builtin(__builtin_elementwise_max) && __has_builtin(__builtin_elementwise_min)
    return __builtin_elementwise_min(
        __builtin_elementwise_max(v, (f32x2){0.f, 0.f}), (f32x2){1.f, 1.f});
#else
    return (f32x2){fminf(fmaxf(v[0], 0.f), 1.f), fminf(fmaxf(v[1], 0.f), 1.f)};
#endif
}

__global__ __launch_bounds__(kThreads, 5) void lattice_fwd(
    const float* __restrict__ x,
    const float* __restrict__ cal_kp,    // [D][K]
    const float* __restrict__ cal_vals,  // [D][K]
    const float* __restrict__ k1,        // [E][4][16]
    const float* __restrict__ k2,        // [E][16]
    float* __restrict__ out)             // [B][E]
{
    __shared__ float sKp[kD * 16];       // kp rows, +INF sentinel       1 KB
    __shared__ f32x4 sEnt[kD * 16];      // {kp, slope, v0, 0}           4 KB
    __shared__ f16x4 sW[4 * 4 * 64];     // [mtile][lattice][lane]       8 KB
    __shared__ f16x4 sK1[4 * 2 * 64];    // [lattice][ntile][lane]       4 KB
    __shared__ float sK2[32 * kK2S];     // [e][0..7]=evens, [8..15]=db 2.5 KB

    const int tid  = threadIdx.x;
    const int lane = tid & 63;
    const int wv   = __builtin_amdgcn_readfirstlane(tid >> 6);   // 0..3
    const int q    = lane >> 4;          // feature-quarter / lattice / row-grp
    const int r15  = lane & 15;          // row in tile (ph1) / col e (ph2)

    const int rowBase = blockIdx.x * kRPB + wv * 16;

    // coalesced x prefetch: wave covers rows rowBase..+15 (1KB contiguous)
    f32x4 xin = *reinterpret_cast<const f32x4*>(
        x + (size_t)(rowBase + r15) * kD + 4 * q);

    // ---------------- phase 0: stage tables ----------------
    sKp[tid] = ((tid & 15) == 15) ? __builtin_inff() : cal_kp[tid];
    if (tid < kD * 15) {
        int d = tid / 15;
        int k = tid - d * 15;
        float kp0 = cal_kp[d * kK + k];
        float kp1 = cal_kp[d * kK + k + 1];
        float v0  = cal_vals[d * kK + k];
        float v1  = cal_vals[d * kK + k + 1];
        float dxv = kp1 - kp0;
        float slope = (dxv > 0.0f) ? (v1 - v0) / dxv : 0.0f;
        sEnt[d * 16 + k] = (f32x4){kp0, slope, v0, 0.0f};
    }
    // k1 B-frags: lane ls holds B[k=4*(ls>>4)+j][col=16n+(ls&15)]
    #pragma unroll
    for (int s0 = 0; s0 < 2; ++s0) {
        int s  = tid + s0 * kThreads;    // 0..511
        int l  = s >> 7;
        int n  = (s >> 6) & 1;
        int ls = s & 63;
        int e  = n * 16 + (ls & 15);
        int g  = ls >> 4;
        f16x4 v = {(_Float16)0.f, (_Float16)0.f, (_Float16)0.f, (_Float16)0.f};
        if (e < kE) {
            const float* src = k1 + ((size_t)(e * 4 + l) * kNV + 4 * g);
            v[0] = (_Float16)src[0]; v[1] = (_Float16)src[1];
            v[2] = (_Float16)src[2]; v[3] = (_Float16)src[3];
        }
        sK1[s] = v;
    }
    // k2: evens + diffs, zero-padded rows for e in [24,32)
    {
        int e = tid >> 3, j = tid & 7;
        float lo = 0.f, hi = 0.f;
        if (e < kE) { lo = k2[e * kNV + 2 * j]; hi = k2[e * kNV + 2 * j + 1]; }
        sK2[e * kK2S + j]     = lo;
        sK2[e * kK2S + 8 + j] = hi - lo;
    }

    __syncthreads();   // the ONLY block-wide barrier

    // ------------- phase 1: calibrate features 4q..4q+3 of row r15 -------------
    float xc[4];
    #pragma unroll
    for (int i = 0; i < 4; ++i) {
        const int d = 4 * q + i;                  // per-lane-group
        const float xv = xin[i];
        const float* kpb = &sKp[d * 16];
        int j = 0;
        #pragma unroll
        for (int s = 8; s >= 1; s >>= 1) {        // 4x: b32 read + cmp + cndmask
            float kps = kpb[j + s];
            j = (xv >= kps) ? j + s : j;
        }
        f32x4 ent = sEnt[d * 16 + j];             // {kp, slope, v0}
        float t = fmaf(ent[1], xv - ent[0], ent[2]);
        xc[i] = fminf(fmaxf(t, 0.0f), 1.0f);      // interp ends + clip_inputs
    }

    // multilinear corner weights for lattice q (dim0 = MSB of corner index)
    float wf[16];
    {
        float a = xc[0], b = xc[1], c = xc[2], d = xc[3];
        float t2[2] = {1.0f - a, a};
        float t4[4];
        #pragma unroll
        for (int j = 0; j < 2; ++j) { t4[2*j] = t2[j]*(1.0f-b); t4[2*j+1] = t2[j]*b; }
        float t8[8];
        #pragma unroll
        for (int j = 0; j < 4; ++j) { t8[2*j] = t4[j]*(1.0f-c); t8[2*j+1] = t4[j]*c; }
        #pragma unroll
        for (int j = 0; j < 8; ++j) { wf[2*j] = t8[j]*(1.0f-d); wf[2*j+1] = t8[j]*d; }
    }

    // A-frags into the wave's OWN M-tile region (m = wv): wave-private
    #pragma unroll
    for (int g = 0; g < 4; ++g) {
        f16x4 v;
        v[0] = (_Float16)wf[4*g+0]; v[1] = (_Float16)wf[4*g+1];
        v[2] = (_Float16)wf[4*g+2]; v[3] = (_Float16)wf[4*g+3];
        sW[(wv * 4 + q) * 64 + r15 + 16 * g] = v;
    }
    // wave-local fence: our 64 lanes' ds_writes complete before our ds_reads
    asm volatile("s_waitcnt lgkmcnt(0)" ::: "memory");

    f16x4 af[4];
    #pragma unroll
    for (int l = 0; l < 4; ++l) af[l] = sW[(wv * 4 + l) * 64 + lane];

    // ---------------- phase 2: MFMA layer-1 + packed layer-2 ----------------
    #pragma unroll
    for (int n = 0; n < 2; ++n) {
        const int e = n * 16 + r15;

        f16x4 bf[4];
        #pragma unroll
        for (int l = 0; l < 4; ++l) bf[l] = sK1[(l * 2 + n) * 64 + lane];

        // k2 evens + diffs for this e (lanes sharing r15 broadcast)
        const float* kr = &sK2[e * kK2S];
        f32x4 ke0 = *reinterpret_cast<const f32x4*>(kr);
        f32x4 ke1 = *reinterpret_cast<const f32x4*>(kr + 4);
        f32x4 kd0 = *reinterpret_cast<const f32x4*>(kr + 8);
        f32x4 kd1 = *reinterpret_cast<const f32x4*>(kr + 12);
        float kbe[8] = {ke0[0],ke0[1],ke0[2],ke0[3], ke1[0],ke1[1],ke1[2],ke1[3]};
        float db [8] = {kd0[0],kd0[1],kd0[2],kd0[3], kd1[0],kd1[1],kd1[2],kd1[3]};

        f32x4 acc[4];
        #pragma unroll
        for (int l = 0; l < 4; ++l)
            acc[l] = __builtin_amdgcn_mfma_f32_16x16x16f16(
                af[l], bf[l], (f32x4){0.f, 0.f, 0.f, 0.f}, 0, 0, 0);

        // layer-2 lerp chain packed across row pairs (acc elems 2p, 2p+1)
        #pragma unroll
        for (int p = 0; p < 2; ++p) {
            f32x2 h0 = clamp01((f32x2){acc[0][2*p], acc[0][2*p+1]});
            f32x2 h1 = clamp01((f32x2){acc[1][2*p], acc[1][2*p+1]});
            f32x2 h2 = clamp01((f32x2){acc[2][2*p], acc[2][2*p+1]});
            f32x2 h3 = clamp01((f32x2){acc[3][2*p], acc[3][2*p+1]});
            f32x2 v8[8];
            #pragma unroll
            for (int j = 0; j < 8; ++j) v8[j] = fma2s(h3, db[j], kbe[j]);
            f32x2 v4[4];
            #pragma unroll
            for (int j = 0; j < 4; ++j) v4[j] = fma2(h2, v8[2*j+1]-v8[2*j], v8[2*j]);
            f32x2 v2[2];
            #pragma unroll
            for (int j = 0; j < 2; ++j) v2[j] = fma2(h1, v4[2*j+1]-v4[2*j], v4[2*j]);
            f32x2 o = fma2(h0, v2[1]-v2[0], v2[0]);
            if (e < kE) {   // exec-masked store (C layout: row=4q+reg, col=e)
                size_t r0 = (size_t)(rowBase + q * 4 + 2 * p);
                out[r0 * kE + e]       = o[0];
                out[(r0 + 1) * kE + e] = o[1];
            }
        }
    }
}

extern "C" void kernel_launch(void* const* d_in, const int* in_sizes, int n_in,
                              void* d_out, int out_size, void* d_ws, size_t ws_size,
                              hipStream_t stream) {
    const float* x        = (const float*)d_in[0];
    const float* cal_kp   = (const float*)d_in[1];
    const float* cal_vals = (const float*)d_in[2];
    const float* k1       = (const float*)d_in[3];
    const float* k2       = (const float*)d_in[4];
    float* out = (float*)d_out;

    hipLaunchKernelGGL(lattice_fwd, dim3(131072 / kRPB), dim3(kThreads), 0, stream,
                       x, cal_kp, cal_vals, k1, k2, out);
}

// Round 8
// 14.133 us; speedup vs baseline: 2.1435x; 1.0067x over previous
//
#include <hip/hip_runtime.h>

// ParallelLatticeModel v8: v7 + LDS bank-conflict elimination (odd-stride
// padding on every hot structure), affine {slope,intercept} calibration
// entries (b64), register-lean epilogue, launch_bounds(256,8) for
// 8 waves/SIMD occupancy.
//
// B=131072 rows, D=16 features, 4 lattices x 4 dims (16 corners), E=24 cols,
// K=16 calibration keypoints.
//
// Block = 256 threads = 4 waves, 64 rows. Wave wv owns rows 16wv..16wv+15.
// Phase 1: lane = r15 + 16q: calibrate features 4q..4q+3 of row r15
//          (binary search in padded sKp, one b64 affine entry), build 16
//          corner weights (lattice q), write fp16 A-frags to the wave's own
//          padded sW region (wave-local lgkmcnt fence, no 2nd barrier).
// Phase 2: 4 lattices x 2 N-tiles of v_mfma_f32_16x16x16_f16 (K=16);
//          C layout col=lane&15, row=4*(lane>>4)+r (test-verified v3-v7);
//          layer-2 lerp chain packed across row pairs (f32x2 v_pk_fma_f32),
//          k2 consumed as per-(e,j4) b128 {A,B,dA,dB} from padded sK2.

typedef _Float16 f16x4 __attribute__((ext_vector_type(4)));
typedef float f32x4 __attribute__((ext_vector_type(4)));
typedef float f32x2 __attribute__((ext_vector_type(2)));

namespace {
constexpr int kD = 16, kE = 24, kK = 16, kNV = 16;
constexpr int kThreads = 256;
constexpr int kRPB = 64;             // rows per block
constexpr int kKpS  = 17;            // sKp row stride (floats)  - odd pad
constexpr int kAffS = 17;            // sAff row stride (f32x2)  - odd pad
constexpr int kWS   = 67;            // sW region stride (f16x4) - odd pad
constexpr int kK2S  = 20;            // sK2 row stride (floats)  - 16B aligned
}

static __device__ __forceinline__ f32x2 fma2(f32x2 a, f32x2 b, f32x2 c) {
#if __has_builtin(__builtin_elementwise_fma)
    return __builtin_elementwise_fma(a, b, c);
#else
    return (f32x2){fmaf(a[0], b[0], c[0]), fmaf(a[1], b[1], c[1])};
#endif
}
static __device__ __forceinline__ f32x2 fma2s(f32x2 a, float b, float c) {
    return fma2(a, (f32x2){b, b}, (f32x2){c, c});
}
static __device__ __forceinline__ f32x2 clamp01(f32x2 v) {
    return (f32x2){fminf(fmaxf(v[0], 0.f), 1.f), fminf(fmaxf(v[1], 0.f), 1.f)};
}

__global__ __launch_bounds__(kThreads, 8) void lattice_fwd(
    const float* __restrict__ x,
    const float* __restrict__ cal_kp,    // [D][K]
    const float* __restrict__ cal_vals,  // [D][K]
    const float* __restrict__ k1,        // [E][4][16]
    const float* __restrict__ k2,        // [E][16]
    float* __restrict__ out)             // [B][E]
{
    __shared__ float sKp[kD * kKpS];     // padded kp rows, +INF sentinel 1.1KB
    __shared__ f32x2 sAff[kD * kAffS];   // {slope, intercept} padded     2.1KB
    __shared__ f16x4 sW[16 * kWS];       // [mtile*lattice padded][lane]  8.4KB
    __shared__ f16x4 sK1[4 * 2 * 64];    // [lattice][ntile][lane]        4 KB
    __shared__ float sK2[32 * kK2S];     // [e][j4]{A,B,dA,dB} padded     2.5KB

    const int tid  = threadIdx.x;
    const int lane = tid & 63;
    const int wv   = __builtin_amdgcn_readfirstlane(tid >> 6);   // 0..3
    const int q    = lane >> 4;          // feature-quarter / lattice
    const int r15  = lane & 15;          // row in tile (ph1) / col e (ph2)

    const int rowBase = blockIdx.x * kRPB + wv * 16;

    // coalesced x prefetch: wave covers rows rowBase..+15 (1KB contiguous)
    f32x4 xin = *reinterpret_cast<const f32x4*>(
        x + (size_t)(rowBase + r15) * kD + 4 * q);

    // ---------------- phase 0: stage tables ----------------
    {   // kp search rows (padded): +INF sentinel at k=15
        int d = tid >> 4, k = tid & 15;
        sKp[d * kKpS + k] = (k == 15) ? __builtin_inff() : cal_kp[tid];
    }
    if (tid < kD * 15) {   // affine entries {slope, intercept}
        int d = tid / 15;
        int k = tid - d * 15;
        float kp0 = cal_kp[d * kK + k];
        float kp1 = cal_kp[d * kK + k + 1];
        float v0  = cal_vals[d * kK + k];
        float v1  = cal_vals[d * kK + k + 1];
        float dxv = kp1 - kp0;
        float slope = (dxv > 0.0f) ? (v1 - v0) / dxv : 0.0f;
        sAff[d * kAffS + k] = (f32x2){slope, fmaf(-slope, kp0, v0)};
    }
    // k1 B-frags: lane ls holds B[k=4*(ls>>4)+j][col=16n+(ls&15)]
    #pragma unroll
    for (int s0 = 0; s0 < 2; ++s0) {
        int s  = tid + s0 * kThreads;    // 0..511
        int l  = s >> 7;
        int n  = (s >> 6) & 1;
        int ls = s & 63;
        int e  = n * 16 + (ls & 15);
        int g  = ls >> 4;
        f16x4 v = {(_Float16)0.f, (_Float16)0.f, (_Float16)0.f, (_Float16)0.f};
        if (e < kE) {
            const float* src = k1 + ((size_t)(e * 4 + l) * kNV + 4 * g);
            v[0] = (_Float16)src[0]; v[1] = (_Float16)src[1];
            v[2] = (_Float16)src[2]; v[3] = (_Float16)src[3];
        }
        sK1[s] = v;
    }
    {   // k2 per-(e,j4) packs {A,B,dA,dB}: A=k2[4j4], B=k2[4j4+2], d*=next-curr
        int e = tid >> 3, j4 = (tid >> 1) & 3, h = tid & 1;
        float a = 0.f, d = 0.f;
        if (e < kE) {
            a = k2[e * kNV + 4 * j4 + 2 * h];
            d = k2[e * kNV + 4 * j4 + 2 * h + 1] - a;
        }
        sK2[e * kK2S + 4 * j4 + h]     = a;
        sK2[e * kK2S + 4 * j4 + 2 + h] = d;
    }

    __syncthreads();   // the ONLY block-wide barrier

    // ------------- phase 1: calibrate features 4q..4q+3 of row r15 -------------
    float xc[4];
    #pragma unroll
    for (int i = 0; i < 4; ++i) {
        const int d = 4 * q + i;
        const float xv = xin[i];
        const float* kpb = &sKp[d * kKpS];
        int j = 0;
        #pragma unroll
        for (int s = 8; s >= 1; s >>= 1) {        // 4x: b32 read + cmp + cndmask
            float kps = kpb[j + s];
            j = (xv >= kps) ? j + s : j;
        }
        f32x2 ent = sAff[d * kAffS + j];          // {slope, intercept}
        xc[i] = fminf(fmaxf(fmaf(ent[0], xv, ent[1]), 0.0f), 1.0f);
    }

    // multilinear corner weights for lattice q (dim0 = MSB of corner index)
    float wf[16];
    {
        float a = xc[0], b = xc[1], c = xc[2], d = xc[3];
        float t2[2] = {1.0f - a, a};
        float t4[4];
        #pragma unroll
        for (int j = 0; j < 2; ++j) { t4[2*j] = t2[j]*(1.0f-b); t4[2*j+1] = t2[j]*b; }
        float t8[8];
        #pragma unroll
        for (int j = 0; j < 4; ++j) { t8[2*j] = t4[j]*(1.0f-c); t8[2*j+1] = t4[j]*c; }
        #pragma unroll
        for (int j = 0; j < 8; ++j) { wf[2*j] = t8[j]*(1.0f-d); wf[2*j+1] = t8[j]*d; }
    }

    // A-frags into the wave's OWN padded M-tile region (wave-private)
    #pragma unroll
    for (int g = 0; g < 4; ++g) {
        f16x4 v;
        v[0] = (_Float16)wf[4*g+0]; v[1] = (_Float16)wf[4*g+1];
        v[2] = (_Float16)wf[4*g+2]; v[3] = (_Float16)wf[4*g+3];
        sW[(wv * 4 + q) * kWS + r15 + 16 * g] = v;
    }
    asm volatile("s_waitcnt lgkmcnt(0)" ::: "memory");   // wave-local fence

    f16x4 af[4];
    #pragma unroll
    for (int l = 0; l < 4; ++l) af[l] = sW[(wv * 4 + l) * kWS + lane];

    // ---------------- phase 2: MFMA layer-1 + packed layer-2 ----------------
    #pragma unroll
    for (int n = 0; n < 2; ++n) {
        const int e = n * 16 + r15;

        f32x4 acc[4];
        #pragma unroll
        for (int l = 0; l < 4; ++l) {
            f16x4 bf = sK1[(l * 2 + n) * 64 + lane];
            acc[l] = __builtin_amdgcn_mfma_f32_16x16x16f16(
                af[l], bf, (f32x4){0.f, 0.f, 0.f, 0.f}, 0, 0, 0);
        }

        // h3/h2 for both row-pairs (p=0: rows 4q+0,1; p=1: rows 4q+2,3)
        f32x2 h3a = clamp01((f32x2){acc[3][0], acc[3][1]});
        f32x2 h3b = clamp01((f32x2){acc[3][2], acc[3][3]});
        f32x2 h2a = clamp01((f32x2){acc[2][0], acc[2][1]});
        f32x2 h2b = clamp01((f32x2){acc[2][2], acc[2][3]});

        f32x2 v4a[4], v4b[4];
        const float* kr = &sK2[e * kK2S];
        #pragma unroll
        for (int j4 = 0; j4 < 4; ++j4) {
            f32x4 kq = *reinterpret_cast<const f32x4*>(kr + 4 * j4); // {A,B,dA,dB}
            f32x2 a0 = fma2s(h3a, kq[2], kq[0]);
            f32x2 b0 = fma2s(h3a, kq[3], kq[1]);
            v4a[j4]  = fma2(h2a, b0 - a0, a0);
            f32x2 a1 = fma2s(h3b, kq[2], kq[0]);
            f32x2 b1 = fma2s(h3b, kq[3], kq[1]);
            v4b[j4]  = fma2(h2b, b1 - a1, a1);
        }

        #pragma unroll
        for (int p = 0; p < 2; ++p) {
            f32x2 h1 = clamp01((f32x2){acc[1][2*p], acc[1][2*p+1]});
            f32x2 h0 = clamp01((f32x2){acc[0][2*p], acc[0][2*p+1]});
            const f32x2* v4 = (p == 0) ? v4a : v4b;   // compile-time select
            f32x2 w0 = fma2(h1, v4[1] - v4[0], v4[0]);
            f32x2 w1 = fma2(h1, v4[3] - v4[2], v4[2]);
            f32x2 o  = fma2(h0, w1 - w0, w0);
            if (e < kE) {   // exec-masked store (C layout: row=4q+2p(+1), col=e)
                size_t r0 = (size_t)(rowBase + q * 4 + 2 * p);
                out[r0 * kE + e]       = o[0];
                out[(r0 + 1) * kE + e] = o[1];
            }
        }
    }
}

extern "C" void kernel_launch(void* const* d_in, const int* in_sizes, int n_in,
                              void* d_out, int out_size, void* d_ws, size_t ws_size,
                              hipStream_t stream) {
    const float* x        = (const float*)d_in[0];
    const float* cal_kp   = (const float*)d_in[1];
    const float* cal_vals = (const float*)d_in[2];
    const float* k1       = (const float*)d_in[3];
    const float* k2       = (const float*)d_in[4];
    float* out = (float*)d_out;

    hipLaunchKernelGGL(lattice_fwd, dim3(131072 / kRPB), dim3(kThreads), 0, stream,
                       x, cal_kp, cal_vals, k1, k2, out);
}